// Round 1
// baseline (37110.153 us; speedup 1.0000x reference)
//
#include <hip/hip_runtime.h>

#define B_   128
#define T_   200
#define TE_  256
#define H_   256
#define PRE_ 128
#define OUT_ 400
#define NTHR 256

__device__ __forceinline__ float sigm_(float x){ return 1.f/(1.f+__expf(-x)); }
__device__ __forceinline__ float tanh_(float x){
  x = fminf(15.f, fmaxf(-15.f, x));
  float e = __expf(2.f*x);
  return 1.f - 2.f/(e+1.f);
}

// wT is [K][N] (transposed), s_in is LDS [K], each thread produces outputs
// j = tid + o*256. 4 k-stripes -> 4 independent FMA chains per output.
template<int K, int N, bool RELU, bool HASB>
__device__ __forceinline__ void matvec(const float* __restrict__ wT,
                                       const float* __restrict__ bias,
                                       const float* __restrict__ s_in,
                                       float* __restrict__ s_out, int tid)
{
  constexpr int NOUT = (N + NTHR - 1) / NTHR;
  float a0[NOUT], a1[NOUT], a2[NOUT], a3[NOUT];
#pragma unroll
  for (int o = 0; o < NOUT; ++o){ a0[o]=0.f; a1[o]=0.f; a2[o]=0.f; a3[o]=0.f; }
#pragma unroll 2
  for (int k = 0; k < K; k += 4){
    float v0 = s_in[k+0], v1 = s_in[k+1], v2 = s_in[k+2], v3 = s_in[k+3];
#pragma unroll
    for (int o = 0; o < NOUT; ++o){
      int j = tid + o*NTHR;
      a0[o] = fmaf(v0, wT[(size_t)(k+0)*N + j], a0[o]);
      a1[o] = fmaf(v1, wT[(size_t)(k+1)*N + j], a1[o]);
      a2[o] = fmaf(v2, wT[(size_t)(k+2)*N + j], a2[o]);
      a3[o] = fmaf(v3, wT[(size_t)(k+3)*N + j], a3[o]);
    }
  }
#pragma unroll
  for (int o = 0; o < NOUT; ++o){
    int j = tid + o*NTHR;
    if ((N % NTHR == 0) || (j < N)){
      float acc = (a0[o]+a1[o]) + (a2[o]+a3[o]);
      if (HASB) acc += bias[j];
      if (RELU) acc = fmaxf(acc, 0.f);
      s_out[j] = acc;
    }
  }
}

// ---------------- transpose all weight matrices in one launch ----------------
struct TD  { const float* src; float* dst; int N; int K; int blk0; };
struct TDs { TD d[12]; };

__global__ __launch_bounds__(NTHR) void transpose_all(TDs P)
{
  int bid = blockIdx.x;
  int m = 0;
#pragma unroll
  for (int i = 1; i < 12; ++i) if (bid >= P.d[i].blk0) m = i;
  const TD t = P.d[m];
  long gid = (long)(bid - t.blk0)*NTHR + threadIdx.x;
  long nk = (long)t.N * t.K;
  if (gid < nk){
    int j = (int)(gid / t.K);
    int k = (int)(gid % t.K);
    t.dst[(size_t)k*t.N + j] = t.src[gid];  // dst[K][N]
  }
}

// ---------------- pmT[b][h][te] = sum_k enc[b,te,k] * wm[h,k] ----------------
__global__ __launch_bounds__(NTHR) void pm_kernel(const float* __restrict__ enc,
                                                  const float* __restrict__ wmT,
                                                  float* __restrict__ pmT)
{
  int tid = threadIdx.x;
  int b  = blockIdx.x / TE_;
  int te = blockIdx.x % TE_;
  __shared__ __align__(16) float row[H_];
  row[tid] = enc[((size_t)b*TE_ + te)*H_ + tid];
  __syncthreads();
  float a0=0.f,a1=0.f,a2=0.f,a3=0.f;
  for (int k = 0; k < H_; k += 4){
    a0 = fmaf(row[k+0], wmT[(size_t)(k+0)*H_ + tid], a0);
    a1 = fmaf(row[k+1], wmT[(size_t)(k+1)*H_ + tid], a1);
    a2 = fmaf(row[k+2], wmT[(size_t)(k+2)*H_ + tid], a2);
    a3 = fmaf(row[k+3], wmT[(size_t)(k+3)*H_ + tid], a3);
  }
  pmT[((size_t)b*H_ + tid)*TE_ + te] = (a0+a1)+(a2+a3);
}

// ---------------- persistent per-batch decoder ----------------
struct DecParams {
  const float *enc, *targets;
  const float *w1T, *b1, *w2T, *b2;
  const float *awihT, *awhhT, *abih, *abhh;
  const float *wqT, *v_attn;
  const float *wpT, *bp;
  const float *g1wihT, *g1whhT, *g1bih, *g1bhh;
  const float *g2wihT, *g2whhT, *g2bih, *g2bhh;
  const float *woT, *bo;
  const float *pmT;
  float *out;
};

__global__ __launch_bounds__(NTHR) void decoder_kernel(DecParams P)
{
  const int tid = threadIdx.x;
  const int b = blockIdx.x;

  __shared__ __align__(16) float s_frame[OUT_];
  __shared__ __align__(16) float s_p1[H_];
  __shared__ __align__(16) float s_x[PRE_+H_];
  __shared__ __align__(16) float s_gi[3*H_];
  __shared__ __align__(16) float s_gh[3*H_];
  __shared__ __align__(16) float s_ah[H_];
  __shared__ __align__(16) float s_h1[H_];
  __shared__ __align__(16) float s_h2[H_];
  __shared__ __align__(16) float s_av[H_];
  __shared__ __align__(16) float s_q[H_];
  __shared__ __align__(16) float s_al[TE_];
  __shared__ __align__(16) float s_xc[2*H_];
  __shared__ __align__(16) float s_dec[H_];
  __shared__ __align__(16) float s_v[H_];
  __shared__ float s_red[8];

  s_ah[tid]=0.f; s_h1[tid]=0.f; s_h2[tid]=0.f; s_av[tid]=0.f;
  s_v[tid] = P.v_attn[tid];
  __syncthreads();

  const float* encb = P.enc + (size_t)b*TE_*H_;
  const float* pmb  = P.pmT + (size_t)b*H_*TE_;
  float* outb = P.out + (size_t)b*T_*OUT_;
  float* alnb = P.out + (size_t)B_*T_*OUT_ + (size_t)b*T_*TE_;

  for (int t = 0; t < T_; ++t){
    // ---- teacher-forced input frame (go-frame at t=0) ----
    if (t == 0){
      for (int i = tid; i < OUT_; i += NTHR) s_frame[i] = 0.f;
    } else {
      const float* fr = P.targets + ((size_t)b*T_ + (t-1))*OUT_;
      for (int i = tid; i < OUT_; i += NTHR) s_frame[i] = fr[i];
    }
    __syncthreads();

    // ---- prenet ----
    matvec<OUT_, H_, true, true>(P.w1T, P.b1, s_frame, s_p1, tid);
    __syncthreads();
    matvec<H_, PRE_, true, true>(P.w2T, P.b2, s_p1, s_x, tid);
    s_x[PRE_+tid] = s_av[tid];                  // x = [p, attn_val]
    __syncthreads();

    // ---- attention GRU ----
    matvec<PRE_+H_, 3*H_, false, true>(P.awihT, P.abih, s_x,  s_gi, tid);
    matvec<H_,      3*H_, false, true>(P.awhhT, P.abhh, s_ah, s_gh, tid);
    __syncthreads();
    {
      float r = sigm_(s_gi[tid]      + s_gh[tid]);
      float z = sigm_(s_gi[H_+tid]   + s_gh[H_+tid]);
      float n = tanh_(s_gi[2*H_+tid] + r*s_gh[2*H_+tid]);
      s_ah[tid] = (1.f-z)*n + z*s_ah[tid];
    }
    __syncthreads();

    // ---- Bahdanau attention ----
    matvec<H_, H_, false, false>(P.wqT, nullptr, s_ah, s_q, tid);
    __syncthreads();
    float e0=0.f,e1=0.f,e2=0.f,e3=0.f;
    for (int h = 0; h < H_; h += 4){
      e0 = fmaf(s_v[h+0], tanh_(pmb[(size_t)(h+0)*TE_+tid] + s_q[h+0]), e0);
      e1 = fmaf(s_v[h+1], tanh_(pmb[(size_t)(h+1)*TE_+tid] + s_q[h+1]), e1);
      e2 = fmaf(s_v[h+2], tanh_(pmb[(size_t)(h+2)*TE_+tid] + s_q[h+2]), e2);
      e3 = fmaf(s_v[h+3], tanh_(pmb[(size_t)(h+3)*TE_+tid] + s_q[h+3]), e3);
    }
    float sc = (e0+e1)+(e2+e3);
    // softmax over TE=256 (one score per thread)
    float m = sc;
    for (int o = 32; o > 0; o >>= 1) m = fmaxf(m, __shfl_down(m, o, 64));
    if ((tid & 63) == 0) s_red[tid>>6] = m;
    __syncthreads();
    m = fmaxf(fmaxf(s_red[0],s_red[1]), fmaxf(s_red[2],s_red[3]));
    float ex = __expf(sc - m);
    float ssum = ex;
    for (int o = 32; o > 0; o >>= 1) ssum += __shfl_down(ssum, o, 64);
    if ((tid & 63) == 0) s_red[4+(tid>>6)] = ssum;
    __syncthreads();
    ssum = (s_red[4]+s_red[5])+(s_red[6]+s_red[7]);
    float al = ex / ssum;
    s_al[tid] = al;
    alnb[(size_t)t*TE_ + tid] = al;
    __syncthreads();
    // attn_val[h] = sum_te al[te] * enc[b,te,h]   (coalesced over h)
    float v0=0.f,v1=0.f,v2=0.f,v3=0.f;
    for (int te = 0; te < TE_; te += 4){
      v0 = fmaf(s_al[te+0], encb[(size_t)(te+0)*H_+tid], v0);
      v1 = fmaf(s_al[te+1], encb[(size_t)(te+1)*H_+tid], v1);
      v2 = fmaf(s_al[te+2], encb[(size_t)(te+2)*H_+tid], v2);
      v3 = fmaf(s_al[te+3], encb[(size_t)(te+3)*H_+tid], v3);
    }
    float av = (v0+v1)+(v2+v3);
    s_av[tid] = av;
    s_xc[tid] = s_ah[tid];
    s_xc[H_+tid] = av;
    __syncthreads();

    // ---- proj to decoder ----
    matvec<2*H_, H_, false, true>(P.wpT, P.bp, s_xc, s_dec, tid);
    __syncthreads();

    // ---- decoder GRU 1 + residual ----
    matvec<H_, 3*H_, false, true>(P.g1wihT, P.g1bih, s_dec, s_gi, tid);
    matvec<H_, 3*H_, false, true>(P.g1whhT, P.g1bhh, s_h1,  s_gh, tid);
    __syncthreads();
    {
      float r = sigm_(s_gi[tid]      + s_gh[tid]);
      float z = sigm_(s_gi[H_+tid]   + s_gh[H_+tid]);
      float n = tanh_(s_gi[2*H_+tid] + r*s_gh[2*H_+tid]);
      float h1n = (1.f-z)*n + z*s_h1[tid];
      s_h1[tid] = h1n;
      s_dec[tid] = h1n + s_dec[tid];
    }
    __syncthreads();

    // ---- decoder GRU 2 + residual ----
    matvec<H_, 3*H_, false, true>(P.g2wihT, P.g2bih, s_dec, s_gi, tid);
    matvec<H_, 3*H_, false, true>(P.g2whhT, P.g2bhh, s_h2,  s_gh, tid);
    __syncthreads();
    {
      float r = sigm_(s_gi[tid]      + s_gh[tid]);
      float z = sigm_(s_gi[H_+tid]   + s_gh[H_+tid]);
      float n = tanh_(s_gi[2*H_+tid] + r*s_gh[2*H_+tid]);
      float h2n = (1.f-z)*n + z*s_h2[tid];
      s_h2[tid] = h2n;
      s_dec[tid] = h2n + s_dec[tid];
    }
    __syncthreads();

    // ---- proj to mel (reuse s_frame as staging) ----
    matvec<H_, OUT_, false, true>(P.woT, P.bo, s_dec, s_frame, tid);
    __syncthreads();
    for (int i = tid; i < OUT_; i += NTHR) outb[(size_t)t*OUT_ + i] = s_frame[i];
    __syncthreads();
  }
}

extern "C" void kernel_launch(void* const* d_in, const int* in_sizes, int n_in,
                              void* d_out, int out_size, void* d_ws, size_t ws_size,
                              hipStream_t stream)
{
  const float* enc   = (const float*)d_in[0];
  const float* tgt   = (const float*)d_in[1];
  const float* pw1   = (const float*)d_in[2];
  const float* pb1   = (const float*)d_in[3];
  const float* pw2   = (const float*)d_in[4];
  const float* pb2   = (const float*)d_in[5];
  const float* awih  = (const float*)d_in[6];
  const float* awhh  = (const float*)d_in[7];
  const float* abih  = (const float*)d_in[8];
  const float* abhh  = (const float*)d_in[9];
  const float* wq    = (const float*)d_in[10];
  const float* wm    = (const float*)d_in[11];
  const float* vat   = (const float*)d_in[12];
  const float* wp    = (const float*)d_in[13];
  const float* bp    = (const float*)d_in[14];
  const float* g1wih = (const float*)d_in[15];
  const float* g1whh = (const float*)d_in[16];
  const float* g1bih = (const float*)d_in[17];
  const float* g1bhh = (const float*)d_in[18];
  const float* g2wih = (const float*)d_in[19];
  const float* g2whh = (const float*)d_in[20];
  const float* g2bih = (const float*)d_in[21];
  const float* g2bhh = (const float*)d_in[22];
  const float* wo    = (const float*)d_in[23];
  const float* bo    = (const float*)d_in[24];

  float* ws = (float*)d_ws;
  size_t off = 0;
  auto alloc = [&](size_t n){ float* p = ws + off; off += n + 256; return p; };

  float* wmT    = alloc((size_t)H_*H_);
  float* w1T    = alloc((size_t)OUT_*H_);
  float* w2T    = alloc((size_t)H_*PRE_);
  float* awihT  = alloc((size_t)(PRE_+H_)*3*H_);
  float* awhhT  = alloc((size_t)H_*3*H_);
  float* wqT    = alloc((size_t)H_*H_);
  float* wpT    = alloc((size_t)2*H_*H_);
  float* g1wihT = alloc((size_t)H_*3*H_);
  float* g1whhT = alloc((size_t)H_*3*H_);
  float* g2wihT = alloc((size_t)H_*3*H_);
  float* g2whhT = alloc((size_t)H_*3*H_);
  float* woT    = alloc((size_t)H_*OUT_);
  float* pmT    = alloc((size_t)B_*H_*TE_);

  TDs td;
  const float* srcs[12] = { wm, pw1, pw2, awih, awhh, wq, wp, g1wih, g1whh, g2wih, g2whh, wo };
  float* dsts[12]       = { wmT, w1T, w2T, awihT, awhhT, wqT, wpT, g1wihT, g1whhT, g2wihT, g2whhT, woT };
  int Ns[12] = { H_, H_, PRE_, 3*H_, 3*H_, H_, H_, 3*H_, 3*H_, 3*H_, 3*H_, OUT_ };
  int Ks[12] = { H_, OUT_, H_, PRE_+H_, H_, H_, 2*H_, H_, H_, H_, H_, H_ };
  int blk = 0;
  for (int i = 0; i < 12; ++i){
    td.d[i].src = srcs[i]; td.d[i].dst = dsts[i];
    td.d[i].N = Ns[i]; td.d[i].K = Ks[i];
    td.d[i].blk0 = blk;
    long nk = (long)Ns[i]*Ks[i];
    blk += (int)((nk + NTHR - 1) / NTHR);
  }
  transpose_all<<<blk, NTHR, 0, stream>>>(td);
  pm_kernel<<<B_*TE_, NTHR, 0, stream>>>(enc, wmT, pmT);

  DecParams P;
  P.enc = enc; P.targets = tgt;
  P.w1T = w1T; P.b1 = pb1; P.w2T = w2T; P.b2 = pb2;
  P.awihT = awihT; P.awhhT = awhhT; P.abih = abih; P.abhh = abhh;
  P.wqT = wqT; P.v_attn = vat;
  P.wpT = wpT; P.bp = bp;
  P.g1wihT = g1wihT; P.g1whhT = g1whhT; P.g1bih = g1bih; P.g1bhh = g1bhh;
  P.g2wihT = g2wihT; P.g2whhT = g2whhT; P.g2bih = g2bih; P.g2bhh = g2bhh;
  P.woT = woT; P.bo = bo;
  P.pmT = pmT;
  P.out = (float*)d_out;

  decoder_kernel<<<B_, NTHR, 0, stream>>>(P);
}

// Round 2
// 13643.695 us; speedup vs baseline: 2.7199x; 2.7199x over previous
//
#include <hip/hip_runtime.h>

#define B_    128
#define T_    200
#define TE_   256
#define H_    256
#define PRE_  128
#define OUT_  400
#define BT_   (B_*T_)          // 25600

__device__ __forceinline__ float sigm_(float x){ return 1.f/(1.f+__expf(-x)); }
__device__ __forceinline__ float tanh_(float x){
  x = fminf(15.f, fmaxf(-15.f, x));
  float e = __expf(2.f*x);
  return 1.f - 2.f/(e+1.f);
}
__device__ __forceinline__ float b2f_lo(unsigned u){ return __uint_as_float(u << 16); }
__device__ __forceinline__ float b2f_hi(unsigned u){ return __uint_as_float(u & 0xffff0000u); }
__device__ __forceinline__ unsigned short f2b(float f){
  unsigned u = __float_as_uint(f);
  unsigned r = (u + 0x7fff + ((u >> 16) & 1)) >> 16;   // RNE
  return (unsigned short)r;
}

// ---------------- transpose/cast: dst[k*N+j] = src[j*Ksrc + col0 + k] ----------------
struct TD { const float* src; void* dst; int N; int Ksrc; int col0; int Keff; int bf16; int blk0; };
struct TDs { TD d[13]; };

__global__ __launch_bounds__(256) void transpose_cast(TDs P)
{
  int bid = blockIdx.x, m = 0;
#pragma unroll
  for (int i = 1; i < 13; ++i) if (bid >= P.d[i].blk0) m = i;
  TD t = P.d[m];
  long gid = (long)(bid - t.blk0)*256 + threadIdx.x;
  long nk = (long)t.N * t.Keff;
  if (gid >= nk) return;
  int k = (int)(gid / t.N);
  int j = (int)(gid % t.N);
  float v = t.src[(size_t)j*t.Ksrc + t.col0 + k];
  if (t.bf16) ((unsigned short*)t.dst)[(size_t)k*t.N + j] = f2b(v);
  else        ((float*)t.dst)[(size_t)k*t.N + j] = v;
}

// ---------------- generic tiled GEMM: C = act(A[M,K] @ WT[K,N] + bias) ----------------
// AMODE: 0 = plain fp32 ptr (lda), 1 = teacher-forced prev-frame loader (targets)
// OUTMODE: 0 = fp32 row-major [M][N], 1 = pm transposed store [b][h][te]
template<int AMODE, bool RELU, int OUTMODE>
__global__ __launch_bounds__(256) void gemm_k(const float* __restrict__ A, int lda,
                                              const float* __restrict__ WT, int N, int K,
                                              const float* __restrict__ bias,
                                              float* __restrict__ C)
{
  const int tid  = threadIdx.x;
  const int row0 = blockIdx.x * 64;
  const int n0   = blockIdx.y * 64;
  __shared__ float As[16][68];
  __shared__ float Bs[16][64];
  const int tx = tid & 15, ty = tid >> 4;
  float acc[4][4];
#pragma unroll
  for (int i = 0; i < 4; ++i)
#pragma unroll
    for (int j = 0; j < 4; ++j) acc[i][j] = 0.f;

  for (int k0 = 0; k0 < K; k0 += 16){
#pragma unroll
    for (int l = 0; l < 4; ++l){
      int idx = tid + l*256;
      int m = idx >> 4, kk = idx & 15;
      float v;
      if (AMODE == 1){
        int r = row0 + m;
        int t = r % T_;
        v = (t == 0) ? 0.f : A[(size_t)(r-1)*OUT_ + k0 + kk];
      } else {
        v = A[(size_t)(row0+m)*lda + k0 + kk];
      }
      As[kk][m] = v;
    }
#pragma unroll
    for (int l = 0; l < 4; ++l){
      int idx = tid + l*256;
      int kk = idx >> 6, j = idx & 63;
      int jg = n0 + j;
      Bs[kk][j] = (jg < N) ? WT[(size_t)(k0+kk)*N + jg] : 0.f;
    }
    __syncthreads();
#pragma unroll
    for (int kk = 0; kk < 16; ++kk){
      float4 a4 = *(const float4*)&As[kk][ty*4];
      float4 b4 = *(const float4*)&Bs[kk][tx*4];
      acc[0][0] = fmaf(a4.x, b4.x, acc[0][0]); acc[0][1] = fmaf(a4.x, b4.y, acc[0][1]);
      acc[0][2] = fmaf(a4.x, b4.z, acc[0][2]); acc[0][3] = fmaf(a4.x, b4.w, acc[0][3]);
      acc[1][0] = fmaf(a4.y, b4.x, acc[1][0]); acc[1][1] = fmaf(a4.y, b4.y, acc[1][1]);
      acc[1][2] = fmaf(a4.y, b4.z, acc[1][2]); acc[1][3] = fmaf(a4.y, b4.w, acc[1][3]);
      acc[2][0] = fmaf(a4.z, b4.x, acc[2][0]); acc[2][1] = fmaf(a4.z, b4.y, acc[2][1]);
      acc[2][2] = fmaf(a4.z, b4.z, acc[2][2]); acc[2][3] = fmaf(a4.z, b4.w, acc[2][3]);
      acc[3][0] = fmaf(a4.w, b4.x, acc[3][0]); acc[3][1] = fmaf(a4.w, b4.y, acc[3][1]);
      acc[3][2] = fmaf(a4.w, b4.z, acc[3][2]); acc[3][3] = fmaf(a4.w, b4.w, acc[3][3]);
    }
    __syncthreads();
  }
#pragma unroll
  for (int i = 0; i < 4; ++i){
    int r = row0 + ty*4 + i;
#pragma unroll
    for (int jj = 0; jj < 4; ++jj){
      int c = n0 + tx*4 + jj;
      if (c < N){
        float v = acc[i][jj] + (bias ? bias[c] : 0.f);
        if (RELU) v = fmaxf(v, 0.f);
        if (OUTMODE == 0){
          C[(size_t)r*N + c] = v;
        } else {
          int b = r / TE_, te = r % TE_;
          C[((size_t)b*H_ + c)*TE_ + te] = v;
        }
      }
    }
  }
}

// ---------------- in-loop K-split matvec helpers (NT = 1024) ----------------
// mv768: K=256, N=768, 4-way K split, 768 active threads, 4 outputs/thread.
__device__ __forceinline__ void mv768(const uint2* __restrict__ w,
                                      const float* __restrict__ sin_,
                                      float* __restrict__ part, int tid)
{
  if (tid >= 768) return;
  const int kg = tid / 192;
  const int jt = tid - kg*192;
  const float4* sin4 = (const float4*)sin_;
  const uint2* wp_ = w + (size_t)(kg*64)*192 + jt;
  float a0=0.f, a1=0.f, a2=0.f, a3=0.f;
#pragma unroll 4
  for (int k4 = 0; k4 < 16; ++k4){
    float4 x = sin4[kg*16 + k4];
    uint2 w0 = wp_[0], w1 = wp_[192], w2 = wp_[384], w3 = wp_[576];
    wp_ += 768;
    a0 = fmaf(x.x, b2f_lo(w0.x), a0); a1 = fmaf(x.x, b2f_hi(w0.x), a1);
    a2 = fmaf(x.x, b2f_lo(w0.y), a2); a3 = fmaf(x.x, b2f_hi(w0.y), a3);
    a0 = fmaf(x.y, b2f_lo(w1.x), a0); a1 = fmaf(x.y, b2f_hi(w1.x), a1);
    a2 = fmaf(x.y, b2f_lo(w1.y), a2); a3 = fmaf(x.y, b2f_hi(w1.y), a3);
    a0 = fmaf(x.z, b2f_lo(w2.x), a0); a1 = fmaf(x.z, b2f_hi(w2.x), a1);
    a2 = fmaf(x.z, b2f_lo(w2.y), a2); a3 = fmaf(x.z, b2f_hi(w2.y), a3);
    a0 = fmaf(x.w, b2f_lo(w3.x), a0); a1 = fmaf(x.w, b2f_hi(w3.x), a1);
    a2 = fmaf(x.w, b2f_lo(w3.y), a2); a3 = fmaf(x.w, b2f_hi(w3.y), a3);
  }
  float* pp = part + kg*768 + jt*4;
  pp[0]=a0; pp[1]=a1; pp[2]=a2; pp[3]=a3;
}

// mv256<KCH>: N=256 outputs, 16-way K split (KCH = K/16), all 1024 threads.
template<int KCH>
__device__ __forceinline__ void mv256(const uint2* __restrict__ w,
                                      const float* __restrict__ sin_,
                                      float* __restrict__ part, int tid)
{
  const int kg = tid >> 6;
  const int jt = tid & 63;
  const float4* sin4 = (const float4*)sin_;
  const uint2* wp_ = w + (size_t)(kg*KCH)*64 + jt;
  float a0=0.f, a1=0.f, a2=0.f, a3=0.f;
#pragma unroll
  for (int k4 = 0; k4 < KCH/4; ++k4){
    float4 x = sin4[(kg*KCH)/4 + k4];
    uint2 w0 = wp_[0], w1 = wp_[64], w2 = wp_[128], w3 = wp_[192];
    wp_ += 256;
    a0 = fmaf(x.x, b2f_lo(w0.x), a0); a1 = fmaf(x.x, b2f_hi(w0.x), a1);
    a2 = fmaf(x.x, b2f_lo(w0.y), a2); a3 = fmaf(x.x, b2f_hi(w0.y), a3);
    a0 = fmaf(x.y, b2f_lo(w1.x), a0); a1 = fmaf(x.y, b2f_hi(w1.x), a1);
    a2 = fmaf(x.y, b2f_lo(w1.y), a2); a3 = fmaf(x.y, b2f_hi(w1.y), a3);
    a0 = fmaf(x.z, b2f_lo(w2.x), a0); a1 = fmaf(x.z, b2f_hi(w2.x), a1);
    a2 = fmaf(x.z, b2f_lo(w2.y), a2); a3 = fmaf(x.z, b2f_hi(w2.y), a3);
    a0 = fmaf(x.w, b2f_lo(w3.x), a0); a1 = fmaf(x.w, b2f_hi(w3.x), a1);
    a2 = fmaf(x.w, b2f_lo(w3.y), a2); a3 = fmaf(x.w, b2f_hi(w3.y), a3);
  }
  float* pp = part + kg*256 + jt*4;
  pp[0]=a0; pp[1]=a1; pp[2]=a2; pp[3]=a3;
}

// ---------------- persistent per-batch decoder (1024 threads) ----------------
struct DP {
  const float *enc, *preGI, *pm;
  const unsigned short *awihA, *awhh, *wq, *wp, *g1wih, *g1whh, *g2wih, *g2whh;
  const float *abhh, *g1bih, *g1bhh, *g2bih, *g2bhh, *bp, *v_attn;
  float *decbuf, *aln;
};

__global__ __launch_bounds__(1024) void decoder_kernel(DP P)
{
  const int tid = threadIdx.x;
  const int b = blockIdx.x;

  __shared__ __align__(16) float s_ah[H_], s_h1[H_], s_h2[H_], s_av[H_], s_q[H_], s_al[TE_], s_dec[H_];
  __shared__ __align__(16) float s_xc[2*H_];
  __shared__ __align__(16) float s_gi[3*H_], s_gh[3*H_];
  __shared__ __align__(16) float s_pA[4096];
  __shared__ __align__(16) float s_pB[3072];
  __shared__ float s_bhh[3*H_], s_1bi[3*H_], s_1bh[3*H_], s_2bi[3*H_], s_2bh[3*H_];
  __shared__ float s_bp[H_], s_v[H_];
  __shared__ float s_red[8];

  if (tid < H_){
    s_ah[tid]=0.f; s_h1[tid]=0.f; s_h2[tid]=0.f; s_av[tid]=0.f;
    s_bp[tid]=P.bp[tid]; s_v[tid]=P.v_attn[tid];
  }
  if (tid < 3*H_){
    s_bhh[tid]=P.abhh[tid];
    s_1bi[tid]=P.g1bih[tid]; s_1bh[tid]=P.g1bhh[tid];
    s_2bi[tid]=P.g2bih[tid]; s_2bh[tid]=P.g2bhh[tid];
  }
  __syncthreads();

  const float* preg  = P.preGI + (size_t)b*T_*3*H_;
  const float4* pm4  = (const float4*)(P.pm  + (size_t)b*H_*TE_);
  const float4* enc4 = (const float4*)(P.enc + (size_t)b*TE_*H_);
  float* aln_b = P.aln + (size_t)b*T_*TE_;
  float* dec_b = P.decbuf + (size_t)b*T_*H_;

  const uint2* awihA2 = (const uint2*)P.awihA;
  const uint2* awhh2  = (const uint2*)P.awhh;
  const uint2* wq2    = (const uint2*)P.wq;
  const uint2* wp2    = (const uint2*)P.wp;
  const uint2* g1wih2 = (const uint2*)P.g1wih;
  const uint2* g1whh2 = (const uint2*)P.g1whh;
  const uint2* g2wih2 = (const uint2*)P.g2wih;
  const uint2* g2whh2 = (const uint2*)P.g2whh;

  for (int t = 0; t < T_; ++t){
    // ---- S1: attention GRU ----
    float gin = (tid < 768) ? preg[(size_t)t*768 + tid] : 0.f;
    mv768(awihA2, s_av, s_pA, tid);
    mv768(awhh2,  s_ah, s_pB, tid);
    __syncthreads();                                   // B1
    if (tid < 768){
      s_gi[tid] = s_pA[tid]+s_pA[768+tid]+s_pA[1536+tid]+s_pA[2304+tid] + gin;
      s_gh[tid] = s_pB[tid]+s_pB[768+tid]+s_pB[1536+tid]+s_pB[2304+tid] + s_bhh[tid];
    }
    __syncthreads();                                   // B2
    if (tid < H_){
      float r = sigm_(s_gi[tid]      + s_gh[tid]);
      float z = sigm_(s_gi[H_+tid]   + s_gh[H_+tid]);
      float n = tanh_(s_gi[2*H_+tid] + r*s_gh[2*H_+tid]);
      s_ah[tid] = (1.f-z)*n + z*s_ah[tid];
    }
    __syncthreads();                                   // B3
    // ---- S2: query projection ----
    mv256<16>(wq2, s_ah, s_pA, tid);
    __syncthreads();                                   // B4
    if (tid < H_){
      float q = 0.f;
#pragma unroll
      for (int g = 0; g < 16; ++g) q += s_pA[g*256 + tid];
      s_q[tid] = q;
    }
    __syncthreads();                                   // B5
    // ---- S3: scores ----
    {
      const int kg = tid >> 6, jt = tid & 63;
      float a0=0.f,a1=0.f,a2=0.f,a3=0.f;
#pragma unroll 4
      for (int hh = 0; hh < 16; ++hh){
        int h = kg*16 + hh;
        float4 pv = pm4[h*64 + jt];
        float qh = s_q[h], vh = s_v[h];
        a0 = fmaf(vh, tanh_(pv.x + qh), a0);
        a1 = fmaf(vh, tanh_(pv.y + qh), a1);
        a2 = fmaf(vh, tanh_(pv.z + qh), a2);
        a3 = fmaf(vh, tanh_(pv.w + qh), a3);
      }
      float* pp = s_pA + kg*256 + jt*4;
      pp[0]=a0; pp[1]=a1; pp[2]=a2; pp[3]=a3;
    }
    __syncthreads();                                   // B6
    float e = 0.f, ex = 0.f;
    if (tid < TE_){
#pragma unroll
      for (int g = 0; g < 16; ++g) e += s_pA[g*256 + tid];
      float m = e;
      for (int o = 32; o; o >>= 1) m = fmaxf(m, __shfl_down(m, o, 64));
      if ((tid & 63) == 0) s_red[tid >> 6] = m;
    }
    __syncthreads();                                   // B7
    if (tid < TE_){
      float m = fmaxf(fmaxf(s_red[0],s_red[1]), fmaxf(s_red[2],s_red[3]));
      ex = __expf(e - m);
      float s = ex;
      for (int o = 32; o; o >>= 1) s += __shfl_down(s, o, 64);
      if ((tid & 63) == 0) s_red[4 + (tid >> 6)] = s;
    }
    __syncthreads();                                   // B8
    if (tid < TE_){
      float s = (s_red[4]+s_red[5])+(s_red[6]+s_red[7]);
      float al = ex / s;
      s_al[tid] = al;
      aln_b[(size_t)t*TE_ + tid] = al;
    }
    __syncthreads();                                   // B9
    // ---- S4: context ----
    {
      const int kg = tid >> 6, jt = tid & 63;
      float a0=0.f,a1=0.f,a2=0.f,a3=0.f;
#pragma unroll 4
      for (int tt = 0; tt < 16; ++tt){
        int te = kg*16 + tt;
        float alv = s_al[te];
        float4 ev = enc4[te*64 + jt];
        a0 = fmaf(alv, ev.x, a0);
        a1 = fmaf(alv, ev.y, a1);
        a2 = fmaf(alv, ev.z, a2);
        a3 = fmaf(alv, ev.w, a3);
      }
      float* pp = s_pA + kg*256 + jt*4;
      pp[0]=a0; pp[1]=a1; pp[2]=a2; pp[3]=a3;
    }
    __syncthreads();                                   // B10
    if (tid < H_){
      float av = 0.f;
#pragma unroll
      for (int g = 0; g < 16; ++g) av += s_pA[g*256 + tid];
      s_av[tid] = av;
      s_xc[tid] = s_ah[tid];
      s_xc[H_ + tid] = av;
    }
    __syncthreads();                                   // B11
    // ---- S5: proj to decoder ----
    mv256<32>(wp2, s_xc, s_pA, tid);
    __syncthreads();                                   // B12
    if (tid < H_){
      float d = s_bp[tid];
#pragma unroll
      for (int g = 0; g < 16; ++g) d += s_pA[g*256 + tid];
      s_dec[tid] = d;
    }
    __syncthreads();                                   // B13
    // ---- S6: decoder GRU 1 + residual ----
    mv768(g1wih2, s_dec, s_pA, tid);
    mv768(g1whh2, s_h1,  s_pB, tid);
    __syncthreads();                                   // B14
    if (tid < 768){
      s_gi[tid] = s_pA[tid]+s_pA[768+tid]+s_pA[1536+tid]+s_pA[2304+tid] + s_1bi[tid];
      s_gh[tid] = s_pB[tid]+s_pB[768+tid]+s_pB[1536+tid]+s_pB[2304+tid] + s_1bh[tid];
    }
    __syncthreads();                                   // B15
    if (tid < H_){
      float r = sigm_(s_gi[tid]      + s_gh[tid]);
      float z = sigm_(s_gi[H_+tid]   + s_gh[H_+tid]);
      float n = tanh_(s_gi[2*H_+tid] + r*s_gh[2*H_+tid]);
      float h1n = (1.f-z)*n + z*s_h1[tid];
      s_h1[tid] = h1n;
      s_dec[tid] += h1n;
    }
    __syncthreads();                                   // B16
    // ---- S7: decoder GRU 2 + residual ----
    mv768(g2wih2, s_dec, s_pA, tid);
    mv768(g2whh2, s_h2,  s_pB, tid);
    __syncthreads();                                   // B17
    if (tid < 768){
      s_gi[tid] = s_pA[tid]+s_pA[768+tid]+s_pA[1536+tid]+s_pA[2304+tid] + s_2bi[tid];
      s_gh[tid] = s_pB[tid]+s_pB[768+tid]+s_pB[1536+tid]+s_pB[2304+tid] + s_2bh[tid];
    }
    __syncthreads();                                   // B18
    if (tid < H_){
      float r = sigm_(s_gi[tid]      + s_gh[tid]);
      float z = sigm_(s_gi[H_+tid]   + s_gh[H_+tid]);
      float n = tanh_(s_gi[2*H_+tid] + r*s_gh[2*H_+tid]);
      float h2n = (1.f-z)*n + z*s_h2[tid];
      s_h2[tid] = h2n;
      float d = s_dec[tid] + h2n;
      s_dec[tid] = d;
      dec_b[(size_t)t*H_ + tid] = d;
    }
    __syncthreads();                                   // B19
  }
}

// ---------------- host ----------------
extern "C" void kernel_launch(void* const* d_in, const int* in_sizes, int n_in,
                              void* d_out, int out_size, void* d_ws, size_t ws_size,
                              hipStream_t stream)
{
  const float* enc   = (const float*)d_in[0];
  const float* tgt   = (const float*)d_in[1];
  const float* pw1   = (const float*)d_in[2];
  const float* pb1   = (const float*)d_in[3];
  const float* pw2   = (const float*)d_in[4];
  const float* pb2   = (const float*)d_in[5];
  const float* awih  = (const float*)d_in[6];
  const float* awhh  = (const float*)d_in[7];
  const float* abih  = (const float*)d_in[8];
  const float* abhh  = (const float*)d_in[9];
  const float* wq    = (const float*)d_in[10];
  const float* wm    = (const float*)d_in[11];
  const float* vat   = (const float*)d_in[12];
  const float* wp    = (const float*)d_in[13];
  const float* bp    = (const float*)d_in[14];
  const float* g1wih = (const float*)d_in[15];
  const float* g1whh = (const float*)d_in[16];
  const float* g1bih = (const float*)d_in[17];
  const float* g1bhh = (const float*)d_in[18];
  const float* g2wih = (const float*)d_in[19];
  const float* g2whh = (const float*)d_in[20];
  const float* g2bih = (const float*)d_in[21];
  const float* g2bhh = (const float*)d_in[22];
  const float* wo    = (const float*)d_in[23];
  const float* bo    = (const float*)d_in[24];

  float* ws = (float*)d_ws;
  size_t off = 0;
  auto alloc = [&](size_t n){ float* p = ws + off; off += (n + 3) & ~(size_t)3; return p; };

  // fp32 transposed weights
  float* wmT    = alloc(65536);
  float* w1T    = alloc(102400);
  float* w2T    = alloc(32768);
  float* awihPT = alloc(98304);
  float* woT    = alloc(102400);
  // bf16 transposed weights (ushort counts = 2x float count)
  unsigned short* awihA16 = (unsigned short*)alloc(98304);
  unsigned short* awhh16  = (unsigned short*)alloc(98304);
  unsigned short* wq16    = (unsigned short*)alloc(32768);
  unsigned short* wp16    = (unsigned short*)alloc(65536);
  unsigned short* g1wih16 = (unsigned short*)alloc(98304);
  unsigned short* g1whh16 = (unsigned short*)alloc(98304);
  unsigned short* g2wih16 = (unsigned short*)alloc(98304);
  unsigned short* g2whh16 = (unsigned short*)alloc(98304);
  // big activation buffers (aliased where lifetimes allow)
  float* pmf    = alloc((size_t)B_*H_*TE_);      // 8,388,608 f ; aliases p2 (3,276,800 f)
  float* decb   = alloc((size_t)BT_*H_);         // 6,553,600 f ; aliases p1 (same size)
  float* preGIf = alloc((size_t)BT_*3*H_);       // 19,660,800 f
  float* p1f = decb;
  float* p2f = pmf;

  // ---- 1. transposes/casts ----
  TDs td;
  const float* srcs[13] = { wm,  pw1, pw2, awih, wo,  awih, awhh, wq,  wp,  g1wih, g1whh, g2wih, g2whh };
  void* dsts[13] = { wmT, w1T, w2T, awihPT, woT, awihA16, awhh16, wq16, wp16, g1wih16, g1whh16, g2wih16, g2whh16 };
  int   Ns[13]   = { 256, 256, 128, 768,  400, 768, 768, 256, 256, 768, 768, 768, 768 };
  int   Kss[13]  = { 256, 400, 256, 384,  256, 384, 256, 256, 512, 256, 256, 256, 256 };
  int   c0s[13]  = { 0,   0,   0,   0,    0,   128, 0,   0,   0,   0,   0,   0,   0 };
  int   Kes[13]  = { 256, 400, 256, 128,  256, 256, 256, 256, 512, 256, 256, 256, 256 };
  int   bfs[13]  = { 0,   0,   0,   0,    0,   1,   1,   1,   1,   1,   1,   1,   1 };
  int blk = 0;
  for (int i = 0; i < 13; ++i){
    td.d[i] = { srcs[i], dsts[i], Ns[i], Kss[i], c0s[i], Kes[i], bfs[i], blk };
    long nk = (long)Ns[i]*Kes[i];
    blk += (int)((nk + 255) / 256);
  }
  transpose_cast<<<blk, 256, 0, stream>>>(td);

  // ---- 2. prenet + preGI (teacher-forced, loop-invariant) ----
  gemm_k<1, true, 0><<<dim3(BT_/64, 4), 256, 0, stream>>>(tgt, 0,   w1T,    256, 400, pb1,  p1f);
  gemm_k<0, true, 0><<<dim3(BT_/64, 2), 256, 0, stream>>>(p1f, 256, w2T,    128, 256, pb2,  p2f);
  gemm_k<0, false,0><<<dim3(BT_/64,12), 256, 0, stream>>>(p2f, 128, awihPT, 768, 128, abih, preGIf);
  // ---- 3. pm = enc @ wm.T, stored [b][h][te]  (overwrites p2 region) ----
  gemm_k<0, false,1><<<dim3((B_*TE_)/64, 4), 256, 0, stream>>>(enc, 256, wmT, 256, 256, nullptr, pmf);

  // ---- 4. recurrence ----
  DP P;
  P.enc = enc; P.preGI = preGIf; P.pm = pmf;
  P.awihA = awihA16; P.awhh = awhh16; P.wq = wq16; P.wp = wp16;
  P.g1wih = g1wih16; P.g1whh = g1whh16; P.g2wih = g2wih16; P.g2whh = g2whh16;
  P.abhh = abhh; P.g1bih = g1bih; P.g1bhh = g1bhh; P.g2bih = g2bih; P.g2bhh = g2bhh;
  P.bp = bp; P.v_attn = vat;
  P.decbuf = decb;
  P.aln = (float*)d_out + (size_t)BT_*OUT_;
  decoder_kernel<<<B_, 1024, 0, stream>>>(P);

  // ---- 5. deferred output projection ----
  gemm_k<0, false,0><<<dim3(BT_/64, 7), 256, 0, stream>>>(decb, 256, woT, 400, 256, bo, (float*)d_out);
}